// Round 9
// baseline (2379.226 us; speedup 1.0000x reference)
//
#include <hip/hip_runtime.h>
#include <math.h>

#define T_TOTAL 262144
#define HID 32
#define WIN 3072                      /* windows: 85-86 serial steps each */
/* window geometry: first 1024 windows have 86 steps, rest 85.
   S(w) = 85*w + min(w,1024); contiguous, covers [0, 262144). */
#define NSWEEP 6                      /* total sweeps; NSWEEP-1 corrections */
#define FD_EPS0 4.0                   /* FD perturbation on s0 (snow) */
#define FD_EPS1 8.0                   /* FD perturbation on s1 (water) */
#define LOG2E 1.4426950408889634f
#define TANH2C 2.8853900817779268f    /* 2*log2e */
#define NEG10LOG2E (-14.426950408889634f)
#define POS10LOG2E (14.426950408889634f)

#define PIN(x) asm volatile("" : "+v"(x))

typedef _Float16 f16x8 __attribute__((ext_vector_type(8)));
typedef float f32x4 __attribute__((ext_vector_type(4)));

__device__ __forceinline__ float fexp2(float x) { return __builtin_amdgcn_exp2f(x); }
__device__ __forceinline__ float frcp(float x)  { return __builtin_amdgcn_rcpf(x); }
__device__ __forceinline__ float fast_sig10(float x) {
    return frcp(1.0f + fexp2(x * NEG10LOG2E));
}
__device__ __forceinline__ float fast_tanh_clamp(float x) { // out_kernel only
    float xc = __builtin_amdgcn_fmed3f(x, -9.0f, 9.0f);
    float u  = fexp2(xc * TANH2C);
    return fmaf(-2.0f, frcp(u + 1.0f), 1.0f);
}
__device__ __forceinline__ float fast_tanh_nc(float x) {
    float u = fexp2(x * TANH2C);
    return fmaf(-2.0f, frcp(u + 1.0f), 1.0f);
}

// ---- DPP / lane helpers ----------------------------------------------------
template <int CTRL>
__device__ __forceinline__ float dpp_add(float v) {
    int t = __builtin_amdgcn_update_dpp(0, __float_as_int(v), CTRL, 0xF, 0xF, true);
    return v + __int_as_float(t);
}
__device__ __forceinline__ float allsum16(float x) {
    x = dpp_add<0xB1>(x);   // quad_perm xor1
    x = dpp_add<0x4E>(x);   // quad_perm xor2
    x = dpp_add<0x141>(x);  // row_half_mirror
    x = dpp_add<0x140>(x);  // row_mirror
    return x;
}
__device__ __forceinline__ int dpp_xor1_i(int v) {
    return __builtin_amdgcn_update_dpp(0, v, 0xB1, 0xF, 0xF, true);
}
__device__ __forceinline__ float rl(float x, int lane) {
    return __int_as_float(__builtin_amdgcn_readlane(__float_as_int(x), lane));
}
__device__ __forceinline__ float bpf(int addr, float x) {
    return __int_as_float(__builtin_amdgcn_ds_bpermute(addr, __float_as_int(x)));
}

// ---------------------------------------------------------------------------
// init: all window ICs = global Y0 guess (f32)
// ---------------------------------------------------------------------------
__global__ void init_kernel(const float* __restrict__ inputs, float2* icg) {
    int w = blockIdx.x * blockDim.x + threadIdx.x;
    if (w < WIN) icg[w] = make_float2(inputs[0], inputs[1]);
}

// ---------------------------------------------------------------------------
// Newton-Parareal sweep, FOUR trajectory slots per wave (3 used):
//   quad 0 = unperturbed, quad 1 = +FD_EPS0 on s0, quads 2,3 = +FD_EPS1 on s1.
// Structure validated R6-R8 (absmax at bf16 floor). WIN=3072 puts 12 blocks
// per CU = 3 waves/SIMD: R8 counters showed chain-bound wall (6320 cyc/step)
// with 24% issue slack (VALUBusy 76% at 2 waves); the third wave saturates
// issue -> ~2400 cyc per window-step (-24%).
// Non-uniform windows: LEN = 86 for wnd<1024 else 85.
// ---------------------------------------------------------------------------
__global__ __launch_bounds__(64, 1) void sweep_kernel(
    const float* __restrict__ inputs,   // (T,5)
    const float* __restrict__ lday,     // (T,)
    const float* __restrict__ W1, const float* __restrict__ b1,
    const float* __restrict__ W2, const float* __restrict__ b2,
    const float* __restrict__ W3, const float* __restrict__ b3,
    float* __restrict__ traj,           // (T,2)
    const float2* __restrict__ icg,     // window ICs (read, f32)
    double2* __restrict__ E)            // end states (write), 3*WIN
{
    const int lane = threadIdx.x;
    const int col  = lane & 15;
    const int quad = lane >> 4;
    const int j32  = lane & 31;
    const int half = lane >> 5;
    const bool odd = (lane & 1) != 0;

    const int wnd  = blockIdx.x;
    const int S    = wnd * 85 + ((wnd < 1024) ? wnd : 1024);
    const int LEN  = (wnd < 1024) ? 86 : 85;
    const int endStep = (S + LEN < T_TOTAL - 1) ? (S + LEN) : (T_TOTAL - 1);

    // layer-1 weights, pre-scaled by 2log2e
    float w1c0 = W1[0 * HID + j32] * TANH2C, w1c1 = W1[1 * HID + j32] * TANH2C;
    float w1c2 = W1[2 * HID + j32] * TANH2C, w1c3 = W1[3 * HID + j32] * TANH2C;
    float b1j = b1[j32] * TANH2C;
    PIN(w1c0); PIN(w1c1); PIN(w1c2); PIN(w1c3); PIN(b1j);

    // W2*2log2e as f16 hi/lo B-fragments
    f16x8 Bhi0, Blo0, Bhi1, Blo1;
#pragma unroll
    for (int jj = 0; jj < 8; ++jj) {
        float w0 = W2[(quad * 8 + jj) * HID + col] * TANH2C;
        float w1v = W2[(quad * 8 + jj) * HID + col + 16] * TANH2C;
        _Float16 h0 = (_Float16)w0, h1v = (_Float16)w1v;
        Bhi0[jj] = h0;  Blo0[jj] = (_Float16)(w0 - (float)h0);
        Bhi1[jj] = h1v; Blo1[jj] = (_Float16)(w1v - (float)h1v);
    }
    PIN(Bhi0); PIN(Blo0); PIN(Bhi1); PIN(Blo1);

    float b2a2 = b2[col] * TANH2C, b2b2 = b2[col + 16] * TANH2C;
    f32x4 cb0 = {b2a2, b2a2, b2a2, b2a2};
    f32x4 cb1 = {b2b2, b2b2, b2b2, b2b2};
    PIN(cb0); PIN(cb1);

    // layer-3 weights: 5 channels per 16-lane quad
    float wca[5], wcb[5];
#pragma unroll
    for (int c = 0; c < 5; ++c) {
        wca[c] = W3[col * 5 + c] * LOG2E;
        wcb[c] = W3[(col + 16) * 5 + c] * LOG2E;
        PIN(wca[c]); PIN(wcb[c]);
    }

    float m0 = (col == 0) ? 1.f : 0.f;
    float m1 = (col == 1) ? 1.f : 0.f;
    float m2 = (col == 2) ? 1.f : 0.f;
    float m3 = (col == 3) ? 1.f : 0.f;
    float m4 = (col == 4) ? 1.f : 0.f;
    float m5 = (col == 5) ? 1.f : 0.f;
    float m6 = (col == 6) ? 1.f : 0.f;
    float m7 = (col == 7) ? 1.f : 0.f;
    float m8 = (col == 8) ? 1.f : 0.f;
    float sig1m = (col >= 5 && col <= 8) ? 1.f : 0.f;
    float zb = b3[(col < 5) ? col : 0];
    float zconst = (col < 5) ? zb * LOG2E : 0.f;
    PIN(m0); PIN(m1); PIN(m2); PIN(m3); PIN(m4); PIN(m5); PIN(m6); PIN(m7); PIN(m8);
    PIN(sig1m); PIN(zconst);

    int psel = (lane & 1) ? 0x01000504 : 0x05040100;
    // A-build gather base by row class r&3: {A,B,C,C-dup} -> {+0,+128,+4,+132}
    int l3 = lane & 3;
    int roff = (l3 == 1) ? 128 : (l3 == 2) ? 4 : (l3 == 3) ? 132 : 0;
    int bbase = 32 * quad + roff;
    int bp0 = bbase, bp1 = bbase + 8, bp2 = bbase + 16, bp3 = bbase + 24;
    PIN(psel); PIN(bp0); PIN(bp1); PIN(bp2); PIN(bp3);

    // per-quad output-gather addresses (bytes)
    int qb = 64 * quad;
    int a_sh0 = qb + 0,  a_sh1 = qb + 4,  a_sh2 = qb + 8;
    int a_e3  = qb + 12, a_e4  = qb + 16, a_sg0 = qb + 20, a_sg1 = qb + 24;
    PIN(a_sh0); PIN(a_sh1); PIN(a_sh2); PIN(a_e3); PIN(a_e4); PIN(a_sg0); PIN(a_sg1);

    float2 ic = icg[wnd];
    double y0 = (double)ic.x + ((quad == 1) ? FD_EPS0 : 0.0);
    double y1 = (double)ic.y + ((quad >= 2) ? FD_EPS1 : 0.0);
    float2* traj2 = (float2*)traj;
    if (lane == 0 && wnd == 0)
        traj2[0] = make_float2(ic.x, ic.y);

    auto rhs = [&](float s0q, float s1q, float base, float stm, float ld, float zoffk,
                   float& d0, float& d1, float& rout) {
        // broadcast the three trajectory states for layer-1
        float s0A = rl(s0q, 0),  s1A = rl(s1q, 0);
        float s0B = rl(s0q, 16), s1B = rl(s1q, 16);
        float s0C = rl(s0q, 32), s1C = rl(s1q, 32);
        float s0p = half ? s0B : s0A;
        float s1p = half ? s1B : s1A;
        // layer-1: primary (A/B by half) and C (all lanes)
        float prep = fmaf(s1p, w1c1, fmaf(s0p, w1c0, base));
        float prec = fmaf(s1C, w1c1, fmaf(s0C, w1c0, base));
        float up_ = fexp2(prep);
        float uc_ = fexp2(prec);
        float h1p = fmaf(-2.0f, frcp(up_ + 1.0f), 1.0f);
        float h1c = fmaf(-2.0f, frcp(uc_ + 1.0f), 1.0f);
        union { _Float16 h; unsigned short u; } cvp, cvc;
        cvp.h = (_Float16)h1p; cvc.h = (_Float16)h1c;
        int ownp = (int)cvp.u, ownc = (int)cvc.u;
        int nbp = dpp_xor1_i(ownp), nbc = dpp_xor1_i(ownc);
        int pkp = __builtin_amdgcn_perm(nbp, ownp, psel);
        int pkc = __builtin_amdgcn_perm(nbc, ownc, psel);
        int pk  = odd ? pkc : pkp;
        int g0i = __builtin_amdgcn_ds_bpermute(bp0, pk);
        int g1i = __builtin_amdgcn_ds_bpermute(bp1, pk);
        int g2i = __builtin_amdgcn_ds_bpermute(bp2, pk);
        int g3i = __builtin_amdgcn_ds_bpermute(bp3, pk);
        union { int i[4]; f16x8 h; } au;
        au.i[0] = g0i; au.i[1] = g1i; au.i[2] = g2i; au.i[3] = g3i;
        f16x8 A = au.h;
        f32x4 zz = {0.f, 0.f, 0.f, 0.f};
        f32x4 chi0 = __builtin_amdgcn_mfma_f32_16x16x32_f16(A, Bhi0, cb0, 0, 0, 0);
        f32x4 clo0 = __builtin_amdgcn_mfma_f32_16x16x32_f16(A, Blo0, zz, 0, 0, 0);
        f32x4 chi1 = __builtin_amdgcn_mfma_f32_16x16x32_f16(A, Bhi1, cb1, 0, 0, 0);
        f32x4 clo1 = __builtin_amdgcn_mfma_f32_16x16x32_f16(A, Blo1, zz, 0, 0, 0);
        // per-quad trajectory row select (C rows: 4q+0=A, +1=B, +2=C, +3=C-dup)
        float tA0 = chi0[0] + clo0[0], tB0 = chi0[1] + clo0[1], tC0 = chi0[2] + clo0[2];
        float tA1 = chi1[0] + clo1[0], tB1 = chi1[1] + clo1[1], tC1 = chi1[2] + clo1[2];
        float t0 = (quad == 1) ? tB0 : (quad >= 2) ? tC0 : tA0;
        float t1 = (quad == 1) ? tB1 : (quad >= 2) ? tC1 : tA1;
        float ua = fexp2(t0);
        float ub = fexp2(t1);
        float g0 = fmaf(-2.0f, frcp(ua + 1.0f), 1.0f);
        float g1 = fmaf(-2.0f, frcp(ub + 1.0f), 1.0f);
        float r0 = fmaf(g0, wca[0], g1 * wcb[0]);
        float r1 = fmaf(g0, wca[1], g1 * wcb[1]);
        float r2 = fmaf(g0, wca[2], g1 * wcb[2]);
        float r3 = fmaf(g0, wca[3], g1 * wcb[3]);
        float r4 = fmaf(g0, wca[4], g1 * wcb[4]);
        float s0r = allsum16(r0);
        float s1r = allsum16(r1);
        float s2r = allsum16(r2);
        float s3r = allsum16(r3);
        float s4r = allsum16(r4);
        float zs0 = s0q * NEG10LOG2E;           // own quad's trajectory
        float zs1 = s1q * NEG10LOG2E;
        float zoff = fmaf(zs0, m5, fmaf(zs1, m6, zoffk));
        float zarg = fmaf(s0r, m0, fmaf(s1r, m1, fmaf(s2r, m2,
                     fmaf(s3r, m3, fmaf(s4r, m4, zoff)))));
        float u = fexp2(zarg);
        float r = frcp(u + sig1m);
        float w = fmaf(0.5f, u, -0.5f * r);
        float sh0 = bpf(a_sh0, w), sh1 = bpf(a_sh1, w), sh2 = bpf(a_sh2, w);
        float e3  = bpf(a_e3, u),  e4  = bpf(a_e4, u);
        float sg0 = bpf(a_sg0, r), sg1 = bpf(a_sg1, r);
        float p_snow = fmaxf(sh0 * stm, 0.f);
        float p_rain = fmaxf(sh1, 0.f);
        float melt   = fmaxf(sg0 * sh2, 0.f);
        float etq    = sg1 * fmaf(e3, ld, e4);
        d0 = p_snow - melt;
        d1 = (p_rain + melt) - etq;
        rout = r;
    };

    float pA = inputs[S * 5 + 2],       tmA = inputs[S * 5 + 3],       ldA = lday[S];
    float pB = inputs[(S + 1) * 5 + 2], tmB = inputs[(S + 1) * 5 + 3], ldB = lday[S + 1];
    float pC = inputs[(S + 2) * 5 + 2], tmC = inputs[(S + 2) * 5 + 3], ldC = lday[S + 2];
    float stmA = fast_sig10(-tmA);
    float stmB = fast_sig10(-tmB);
    float stmm = fast_sig10(-0.5f * (tmA + tmB));
    float baseA = fmaf(pA, w1c2, fmaf(tmA, w1c3, b1j));
    float baseB = fmaf(pB, w1c2, fmaf(tmB, w1c3, b1j));

    for (int n = S; n < endStep; ++n) {
        const float ldm = 0.5f * (ldA + ldB);
        const float pm  = 0.5f * (pA + pB);
        const float tmm = 0.5f * (tmA + tmB);
        const float basem = fmaf(pm, w1c2, fmaf(tmm, w1c3, b1j));
        const float ztm_m = (0.5f * (tmB + tmC)) * POS10LOG2E;
        const float ztm_b = tmC * POS10LOG2E;
        const float zoffk = fmaf(ztm_m, m7, fmaf(ztm_b, m8, zconst));

        const float fy0 = (float)y0, fy1 = (float)y1;
        float k10, k11, k20, k21, k30, k31, k40, k41, rd;
        rhs(fy0,                  fy1,                  baseA, stmA, ldA, zoffk, k10, k11, rd);
        rhs(fmaf(0.5f, k10, fy0), fmaf(0.5f, k11, fy1), basem, stmm, ldm, zoffk, k20, k21, rd);
        rhs(fmaf(0.5f, k20, fy0), fmaf(0.5f, k21, fy1), basem, stmm, ldm, zoffk, k30, k31, rd);
        rhs(fy0 + k30,            fy1 + k31,            baseB, stmB, ldB, zoffk, k40, k41, rd);
        const float stmm_n = rl(rd, 7);
        const float stmB_n = rl(rd, 8);

        const float s0sum = (k10 + 2.0f * k20) + (2.0f * k30 + k40);
        const float s1sum = (k11 + 2.0f * k21) + (2.0f * k31 + k41);
        y0 += (1.0 / 6.0) * (double)s0sum;
        y1 += (1.0 / 6.0) * (double)s1sum;

        if (lane == 0)
            traj2[n + 1] = make_float2((float)y0, (float)y1);

        stmA = stmB; stmB = stmB_n; stmm = stmm_n;
        baseA = baseB;
        baseB = fmaf(pC, w1c2, fmaf(tmC, w1c3, b1j));
        pA = pB; tmA = tmB; ldA = ldB;
        pB = pC; tmB = tmC; ldB = ldC;
        const int np3 = (n + 3 < T_TOTAL) ? (n + 3) : (T_TOTAL - 1);
        pC = inputs[np3 * 5 + 2]; tmC = inputs[np3 * 5 + 3]; ldC = lday[np3];
    }

    if (lane == 0)  E[wnd]           = make_double2(y0, y1);  // unperturbed
    if (lane == 16) E[WIN + wnd]     = make_double2(y0, y1);  // +eps0 on s0
    if (lane == 32) E[2 * WIN + wnd] = make_double2(y0, y1);  // +eps1 on s1
}

// ---------------------------------------------------------------------------
// Sequential Newton-Parareal correction (f32 recurrence, R8-validated).
// WIN=3072: 5 staged arrays (J00,J10,J11,E0x,E0y) = 60 KB LDS (<=64 KB);
// old icg (G) no longer fits -> read from global (L2-warm) with an 8-deep
// NAMED-register software pipeline: the 8x~28-cyc f32 chain per group covers
// the ~200-cyc L2 latency of the next group's loads.
// Clamps wide-open for short windows (R6-validated). J01 := 0.
// ---------------------------------------------------------------------------
__global__ __launch_bounds__(64) void correct_kernel(
    const float* __restrict__ inputs,
    const double2* __restrict__ E,
    float2* __restrict__ icg) {
    __shared__ float sJ00[WIN], sJ10[WIN], sJ11[WIN];
    __shared__ float sE0x[WIN], sE0y[WIN];          // 5*3072*4 = 61440 B
    for (int i = threadIdx.x; i < WIN; i += 64) {
        double2 e0 = E[i];
        double2 e1 = E[WIN + i];
        double2 e2 = E[2 * WIN + i];
        float J00 = (float)((e1.x - e0.x) * (1.0 / FD_EPS0));
        float J10 = (float)((e1.y - e0.y) * (1.0 / FD_EPS0));
        float J11 = (float)((e2.y - e0.y) * (1.0 / FD_EPS1));
        sJ00[i] = fminf(fmaxf(J00, -0.15f), 1.15f);   // wide-open (R6)
        sJ10[i] = fminf(fmaxf(J10, -0.30f), 1.80f);
        sJ11[i] = fminf(fmaxf(J11,  0.00f), 1.10f);
        sE0x[i] = (float)e0.x; sE0y[i] = (float)e0.y;
    }
    __syncthreads();
    if (threadIdx.x != 0) return;

    float y0c = inputs[0];
    float y1c = inputs[1];

#define PROC(G, W)                                              \
    {                                                           \
        float d0 = y0c - (G).x;                                 \
        float d1 = y1c - (G).y;                                 \
        d0 = fminf(fmaxf(d0, -50.0f), 50.0f);                   \
        d1 = fminf(fmaxf(d1, -400.0f), 400.0f);                 \
        icg[W] = make_float2(y0c, y1c);                         \
        y0c = fmaf(sJ00[W], d0, sE0x[W]);                       \
        y1c = fmaf(sJ10[W], d0, fmaf(sJ11[W], d1, sE0y[W]));    \
        y0c = fminf(fmaxf(y0c, -5.0f), 1000.0f);                \
        y1c = fminf(fmaxf(y1c, -5.0f), 5000.0f);                \
    }

    float2 g0 = icg[0], g1 = icg[1], g2 = icg[2], g3 = icg[3];
    float2 g4 = icg[4], g5 = icg[5], g6 = icg[6], g7 = icg[7];
    for (int base = 0; base < WIN; base += 8) {
        int nb = base + 8;
        float2 t0, t1, t2, t3, t4, t5, t6, t7;
        if (nb < WIN) {
            t0 = icg[nb + 0]; t1 = icg[nb + 1]; t2 = icg[nb + 2]; t3 = icg[nb + 3];
            t4 = icg[nb + 4]; t5 = icg[nb + 5]; t6 = icg[nb + 6]; t7 = icg[nb + 7];
        } else {
            t0 = g0; t1 = g1; t2 = g2; t3 = g3; t4 = g4; t5 = g5; t6 = g6; t7 = g7;
        }
        PROC(g0, base + 0); PROC(g1, base + 1); PROC(g2, base + 2); PROC(g3, base + 3);
        PROC(g4, base + 4); PROC(g5, base + 5); PROC(g6, base + 6); PROC(g7, base + 7);
        g0 = t0; g1 = t1; g2 = t2; g3 = t3; g4 = t4; g5 = t5; g6 = t6; g7 = t7;
    }
#undef PROC
}

// ---------------------------------------------------------------------------
// Parallel readout: out[t] = mlp(relu(state), p, tm)[4]
// ---------------------------------------------------------------------------
__global__ __launch_bounds__(256) void out_kernel(
    const float* __restrict__ inputs,
    const float* __restrict__ traj,
    const float* __restrict__ W1, const float* __restrict__ b1,
    const float* __restrict__ W2, const float* __restrict__ b2,
    const float* __restrict__ W3, const float* __restrict__ b3,
    float* __restrict__ out)
{
    __shared__ float sW1[4 * HID];
    __shared__ float sb1[HID];
    __shared__ float sW2T[HID * HID];
    __shared__ float sb2[HID];
    __shared__ float sw3[HID];
    for (int i = threadIdx.x; i < 4 * HID; i += 256) sW1[i] = W1[i];
    for (int i = threadIdx.x; i < HID; i += 256) {
        sb1[i] = b1[i]; sb2[i] = b2[i]; sw3[i] = W3[i * 5 + 4];
    }
    for (int idx = threadIdx.x; idx < HID * HID; idx += 256) {
        int jj = idx >> 5, ii = idx & 31;
        sW2T[idx] = W2[ii * HID + jj];
    }
    __syncthreads();

    int t = blockIdx.x * 256 + threadIdx.x;
    if (t >= T_TOTAL) return;

    float2 st = ((const float2*)traj)[t];
    float s0 = fmaxf(st.x, 0.0f);
    float s1 = fmaxf(st.y, 0.0f);
    float p  = inputs[t * 5 + 2];
    float tm = inputs[t * 5 + 3];

    float h1[HID];
#pragma unroll
    for (int jj = 0; jj < HID; ++jj) {
        float pre = fmaf(s0, sW1[jj], fmaf(s1, sW1[HID + jj],
                    fmaf(p, sW1[2 * HID + jj],
                    fmaf(tm, sW1[3 * HID + jj], sb1[jj]))));
        h1[jj] = fast_tanh_clamp(pre);
    }
    float o = b3[4];
#pragma unroll 4
    for (int jj = 0; jj < HID; ++jj) {
        float a0 = sb2[jj], a1 = 0.f, a2 = 0.f, a3 = 0.f;
#pragma unroll
        for (int ii = 0; ii < HID; ii += 4) {
            a0 = fmaf(h1[ii + 0], sW2T[jj * HID + ii + 0], a0);
            a1 = fmaf(h1[ii + 1], sW2T[jj * HID + ii + 1], a1);
            a2 = fmaf(h1[ii + 2], sW2T[jj * HID + ii + 2], a2);
            a3 = fmaf(h1[ii + 3], sW2T[jj * HID + ii + 3], a3);
        }
        o = fmaf(fast_tanh_nc((a0 + a1) + (a2 + a3)), sw3[jj], o);
    }
    out[t] = o;
}

extern "C" void kernel_launch(void* const* d_in, const int* in_sizes, int n_in,
                              void* d_out, int out_size, void* d_ws, size_t ws_size,
                              hipStream_t stream) {
    (void)in_sizes; (void)n_in; (void)out_size; (void)ws_size;
    const float* inputs = (const float*)d_in[0];
    const float* lday   = (const float*)d_in[1];
    const float* W1     = (const float*)d_in[2];
    const float* b1     = (const float*)d_in[3];
    const float* W2     = (const float*)d_in[4];
    const float* b2     = (const float*)d_in[5];
    const float* W3     = (const float*)d_in[6];
    const float* b3     = (const float*)d_in[7];
    float* out  = (float*)d_out;
    float* traj = (float*)d_ws;                 // T*2 floats = 2 MB

    // small Parareal arrays live in d_out (scratch until out_kernel, 1 MB)
    // E = 3*WIN double2 = 147456 B at offset 0; icg = WIN float2 = 24576 B
    // at offset 196608. Total 221184 <= 1 MB.
    char* scr = (char*)d_out;
    double2* E  = (double2*)scr;
    float2* icg = (float2*)(scr + 196608);

    hipLaunchKernelGGL(init_kernel, dim3((WIN + 255) / 256), dim3(256), 0, stream,
                       inputs, icg);
    for (int k = 0; k < NSWEEP - 1; ++k) {
        hipLaunchKernelGGL(sweep_kernel, dim3(WIN), dim3(64), 0, stream,
                           inputs, lday, W1, b1, W2, b2, W3, b3, traj, icg, E);
        hipLaunchKernelGGL(correct_kernel, dim3(1), dim3(64), 0, stream,
                           inputs, E, icg);
    }
    // final sweep: trajectory becomes self-consistent with corrected ICs
    hipLaunchKernelGGL(sweep_kernel, dim3(WIN), dim3(64), 0, stream,
                       inputs, lday, W1, b1, W2, b2, W3, b3, traj, icg, E);
    hipLaunchKernelGGL(out_kernel, dim3((T_TOTAL + 255) / 256), dim3(256), 0, stream,
                       inputs, traj, W1, b1, W2, b2, W3, b3, out);
}